// Round 2
// baseline (244.950 us; speedup 1.0000x reference)
//
#include <hip/hip_runtime.h>
#include <hip/hip_bf16.h>
#include <math.h>

#define S_LEN 2048
#define HID 2048
#define NH 16
#define NKH 8
#define HD 128
#define QKV_N 4096
#define SCALE 0.08838834764831845f
#define EPS 1e-6f
#define LOG2E 1.4426950408889634f
#define QSCALE (SCALE * LOG2E)     // fold log2(e) into q so p = exp2(score)

typedef __hip_bfloat16 bf16;
typedef unsigned int u32;
typedef __bf16 bf16x8 __attribute__((ext_vector_type(8)));
typedef float f32x4 __attribute__((ext_vector_type(4)));

#define MFMA(a, b, c) __builtin_amdgcn_mfma_f32_16x16x32_bf16(a, b, c, 0, 0, 0)

static __device__ __forceinline__ bf16x8 ld_frag(const bf16* p) {
    return __builtin_bit_cast(bf16x8, *(const uint4*)p);
}

// async global->LDS, 16 B per lane. LDS dest = wave-uniform base + lane*16.
static __device__ __forceinline__ void gload_lds16(const void* g, void* l) {
    __builtin_amdgcn_global_load_lds(
        (const __attribute__((address_space(1))) u32*)g,
        (__attribute__((address_space(3))) u32*)l, 16, 0, 0);
}

// ---------------------------------------------------------------------------
// merged fp32 -> bf16: hidden | Wq | Wk | Wv | Wo in one launch.
// float4-unit thresholds: 1M | 2M | 2.5M | 3M | 4M. grid = 16384 x 256.
// ---------------------------------------------------------------------------
__global__ __launch_bounds__(256) void cvt5(
    const float* __restrict__ s0, const float* __restrict__ s1,
    const float* __restrict__ s2, const float* __restrict__ s3,
    const float* __restrict__ s4,
    bf16* __restrict__ d0, bf16* __restrict__ d1, bf16* __restrict__ d2,
    bf16* __restrict__ d3, bf16* __restrict__ d4)
{
    int i = blockIdx.x * 256 + threadIdx.x;
    const float* s; bf16* d; int off;
    if (i < (1 << 20))                   { s = s0; d = d0; off = 0; }
    else if (i < (2 << 20))              { s = s1; d = d1; off = 1 << 20; }
    else if (i < (2 << 20) + (1 << 19))  { s = s2; d = d2; off = 2 << 20; }
    else if (i < (3 << 20))              { s = s3; d = d3; off = (2 << 20) + (1 << 19); }
    else                                 { s = s4; d = d4; off = 3 << 20; }
    int j = i - off;
    float4 v = ((const float4*)s)[j];
    bf16* p = d + 4 * (size_t)j;
    p[0] = __float2bfloat16(v.x);
    p[1] = __float2bfloat16(v.y);
    p[2] = __float2bfloat16(v.z);
    p[3] = __float2bfloat16(v.w);
}

// ---------------------------------------------------------------------------
// QKV GEMM + fused epilogue — REVERTED to the proven R0 structure.
// 128x128 tiles, BK=64, DOUBLE-BUFFERED global_load_lds staging
// (1 barrier/iter, 2 blocks/CU -> cross-block overlap covers barrier drain).
// Wave = 64x64 quadrant as 4x4 MFMA grid -> 8 LDS reads per 16 MFMA.
// Column tiles interleaved (wcg + (j&1)*16 + (j>>1)*64) so the RoPE pair
// (d, d+64) = regs (j, j+2) of the SAME lane. RMSNorm sumsq crosses the
// 2 column-waves -> red[] LDS exchange + 1 barrier.
//   q heads: RMSNorm(qw)+RoPE, * SCALE*LOG2E -> qkvb
//   k heads: RMSNorm(kw)+RoPE -> qkvb; row 2047 -> knew (fp32)
//   v heads: raw -> vT transposed (packed uint2); row 2047 -> vnew
// ---------------------------------------------------------------------------
__global__ __launch_bounds__(256, 2) void gemm_qkv(
    const bf16* __restrict__ A, const bf16* __restrict__ B,
    bf16* __restrict__ qkvb, bf16* __restrict__ vT,
    const float* __restrict__ fcos, const float* __restrict__ fsin,
    const float* __restrict__ qw, const float* __restrict__ kw,
    float* __restrict__ knew, float* __restrict__ vnew)
{
    __shared__ bf16 As[2][128 * 64];
    __shared__ bf16 Bs[2][128 * 64];
    __shared__ float red[2][2][64];    // [row-half][col-wave][row]
    const int tid = threadIdx.x;
    const int n0 = blockIdx.x * 128, m0 = blockIdx.y * 128;
    const int w = tid >> 6, lane = tid & 63;
    const int l15 = lane & 15, quad = lane >> 4;
    const int wr = (w >> 1) * 64;      // wave row base
    const int wcg = (w & 1) * 32;      // wave column group base

    f32x4 acc[4][4];
    #pragma unroll
    for (int i = 0; i < 4; ++i)
        #pragma unroll
        for (int j = 0; j < 4; ++j)
            acc[i][j] = f32x4{0.f, 0.f, 0.f, 0.f};

    // staging: chunk = 8 rows x 64 k; lane -> row (lane>>3), phys slot lane&7
    const int srow8 = lane >> 3;
    const int sls = ((lane & 7) ^ srow8) * 8;   // logical k-slot fetched

    auto stage = [&](int k0, int nb) {
        #pragma unroll
        for (int j = 0; j < 8; ++j) {
            int c = 8 * w + j;                 // 0..31: 16 A-chunks, 16 B-chunks
            if (c < 16) {
                int row = c * 8 + srow8;
                gload_lds16(A + (size_t)(m0 + row) * HID + k0 + sls, &As[nb][c * 512]);
            } else {
                int row = (c - 16) * 8 + srow8;
                gload_lds16(B + (size_t)(n0 + row) * HID + k0 + sls, &Bs[nb][(c - 16) * 512]);
            }
        }
    };

    stage(0, 0);
    for (int kt = 0; kt < HID / 64; ++kt) {
        const int pp = kt & 1;
        __syncthreads();                       // drains stage(kt) -> buf pp ready
        if (kt + 1 < HID / 64) stage((kt + 1) * 64, pp ^ 1);

        #pragma unroll
        for (int kc = 0; kc < 2; ++kc) {
            const int ph = ((kc * 4 + quad) ^ (l15 & 7)) * 8;
            bf16x8 av[4], bv[4];
            #pragma unroll
            for (int i = 0; i < 4; ++i)
                av[i] = ld_frag(&As[pp][(wr + i * 16 + l15) * 64 + ph]);
            #pragma unroll
            for (int j = 0; j < 4; ++j)
                bv[j] = ld_frag(&Bs[pp][(wcg + (j & 1) * 16 + (j >> 1) * 64 + l15) * 64 + ph]);
            #pragma unroll
            for (int i = 0; i < 4; ++i)
                #pragma unroll
                for (int j = 0; j < 4; ++j)
                    acc[i][j] = MFMA(av[i], bv[j], acc[i][j]);
        }
    }

    const int hblk = n0 >> 7;          // 0..15 q | 16..23 k | 24..31 v
    if (hblk < 24) {
        // ---- cross-wave sumsq exchange ----
        float ssq[4][4];
        #pragma unroll
        for (int i = 0; i < 4; ++i)
            #pragma unroll
            for (int rr = 0; rr < 4; ++rr) {
                float ss = 0.f;
                #pragma unroll
                for (int j = 0; j < 4; ++j) ss += acc[i][j][rr] * acc[i][j][rr];
                ss += __shfl_xor(ss, 1);
                ss += __shfl_xor(ss, 2);
                ss += __shfl_xor(ss, 4);
                ss += __shfl_xor(ss, 8);
                ssq[i][rr] = ss;
                if (l15 == 0)
                    red[w >> 1][w & 1][i * 16 + quad * 4 + rr] = ss;
            }
        __syncthreads();

        const float* wgt = (hblk < 16) ? qw : kw;
        float wv[4];
        #pragma unroll
        for (int j = 0; j < 4; ++j)
            wv[j] = wgt[wcg + (j & 1) * 16 + (j >> 1) * 64 + l15];
        const size_t cb = (hblk < 16) ? (size_t)hblk * HD
                                      : (size_t)HID + (size_t)(hblk - 16) * HD;

        #pragma unroll
        for (int i = 0; i < 4; ++i)
            #pragma unroll
            for (int rr = 0; rr < 4; ++rr) {
                int rloc = i * 16 + quad * 4 + rr;
                int srow = m0 + wr + rloc;
                float tot = ssq[i][rr] + red[w >> 1][(w & 1) ^ 1][rloc];
                float rrn = rsqrtf(tot * (1.0f / 128.0f) + EPS);
                float x[4], res[4];
                #pragma unroll
                for (int j = 0; j < 4; ++j) x[j] = acc[i][j][rr] * rrn * wv[j];
                #pragma unroll
                for (int j2 = 0; j2 < 2; ++j2) {
                    float c = fcos[srow * 64 + wcg + j2 * 16 + l15];
                    float s = fsin[srow * 64 + wcg + j2 * 16 + l15];
                    res[j2]     = x[j2] * c - x[j2 + 2] * s;
                    res[j2 + 2] = x[j2] * s + x[j2 + 2] * c;
                }
                if (hblk < 16) {
                    #pragma unroll
                    for (int j = 0; j < 4; ++j)
                        qkvb[(size_t)srow * QKV_N + cb + wcg + (j & 1) * 16 +
                             (j >> 1) * 64 + l15] = __float2bfloat16(res[j] * QSCALE);
                } else {
                    #pragma unroll
                    for (int j = 0; j < 4; ++j)
                        qkvb[(size_t)srow * QKV_N + cb + wcg + (j & 1) * 16 +
                             (j >> 1) * 64 + l15] = __float2bfloat16(res[j]);
                    if (srow == S_LEN - 1) {
                        #pragma unroll
                        for (int j = 0; j < 4; ++j)
                            knew[(hblk - 16) * HD + wcg + (j & 1) * 16 +
                                 (j >> 1) * 64 + l15] = res[j];
                    }
                }
            }
    } else {
        const int kh = hblk - 24;
        #pragma unroll
        for (int i = 0; i < 4; ++i) {
            int rowbase = m0 + wr + i * 16 + quad * 4;
            #pragma unroll
            for (int j = 0; j < 4; ++j) {
                int d = wcg + (j & 1) * 16 + (j >> 1) * 64 + l15;
                union { uint2 u; bf16 hh[4]; } pk;
                #pragma unroll
                for (int r = 0; r < 4; ++r)
                    pk.hh[r] = __float2bfloat16(acc[i][j][r]);
                *(uint2*)&vT[(size_t)(kh * HD + d) * S_LEN + rowbase] = pk.u;
                if (rowbase == S_LEN - 4)
                    vnew[kh * HD + d] = acc[i][j][3];
            }
        }
    }
}

// ---------------------------------------------------------------------------
// Out-projection GEMM — R2: 128x128 tiles (was 128x64), BK=64, dbuf,
// fp32 out. Proven m97 geometry: 16 MFMA per 8 ds_reads (was 8 per 6),
// grid 16x16 = 256 blocks = 1/CU, A-refetch halved. LDS 64 KB, 2 blocks/CU.
// ---------------------------------------------------------------------------
__global__ __launch_bounds__(256, 2) void gemm_n128(
    const bf16* __restrict__ A, const bf16* __restrict__ B,
    float* __restrict__ C, int M, int N, int K)
{
    __shared__ bf16 As[2][128 * 64];
    __shared__ bf16 Bs[2][128 * 64];
    const int tid = threadIdx.x;
    const int n0 = blockIdx.x * 128, m0 = blockIdx.y * 128;
    const int w = tid >> 6, lane = tid & 63;
    const int l15 = lane & 15, quad = lane >> 4;
    const int wr = (w >> 1) * 64;
    const int wc = (w & 1) * 64;

    f32x4 acc[4][4];
    #pragma unroll
    for (int i = 0; i < 4; ++i)
        #pragma unroll
        for (int j = 0; j < 4; ++j)
            acc[i][j] = f32x4{0.f, 0.f, 0.f, 0.f};

    const int srow8 = lane >> 3;
    const int sls = ((lane & 7) ^ srow8) * 8;

    auto stage = [&](int k0, int nb) {
        #pragma unroll
        for (int j = 0; j < 8; ++j) {
            int c = 8 * w + j;                 // 0..31: 16 A-chunks, 16 B-chunks
            if (c < 16) {
                int row = c * 8 + srow8;
                gload_lds16(A + (size_t)(m0 + row) * K + k0 + sls, &As[nb][c * 512]);
            } else {
                int row = (c - 16) * 8 + srow8;
                gload_lds16(B + (size_t)(n0 + row) * K + k0 + sls, &Bs[nb][(c - 16) * 512]);
            }
        }
    };

    stage(0, 0);
    for (int kt = 0; kt < K / 64; ++kt) {
        const int pp = kt & 1;
        __syncthreads();
        if (kt + 1 < K / 64) stage((kt + 1) * 64, pp ^ 1);

        #pragma unroll
        for (int kc = 0; kc < 2; ++kc) {
            const int ph = ((kc * 4 + quad) ^ (l15 & 7)) * 8;
            bf16x8 av[4], bv[4];
            #pragma unroll
            for (int i = 0; i < 4; ++i)
                av[i] = ld_frag(&As[pp][(wr + i * 16 + l15) * 64 + ph]);
            #pragma unroll
            for (int j = 0; j < 4; ++j)
                bv[j] = ld_frag(&Bs[pp][(wc + j * 16 + l15) * 64 + ph]);
            #pragma unroll
            for (int i = 0; i < 4; ++i)
                #pragma unroll
                for (int j = 0; j < 4; ++j)
                    acc[i][j] = MFMA(av[i], bv[j], acc[i][j]);
        }
    }

    #pragma unroll
    for (int i = 0; i < 4; ++i)
        #pragma unroll
        for (int j = 0; j < 4; ++j)
            #pragma unroll
            for (int r = 0; r < 4; ++r)
                C[(size_t)(m0 + wr + i * 16 + quad * 4 + r) * N +
                  n0 + wc + j * 16 + l15] = acc[i][j][r];
}

// ---------------------------------------------------------------------------
// Flash attention — R2: + T5 setprio(1) around both MFMA clusters
// (m191: +4-7% on attn, within-probe A/B; attn blocks are independently
// phased so the CU scheduler has something to arbitrate).
// Fixed-reference softmax, K-tile 64, async double-buffered staging.
// grid (32,16), 4 waves x 16 q-rows.
// ---------------------------------------------------------------------------
__global__ __launch_bounds__(256, 2) void attn_mfma(
    const bf16* __restrict__ qkvb, const bf16* __restrict__ vT,
    bf16* __restrict__ outb)
{
    __shared__ bf16 Ks[2][64 * 128];
    __shared__ bf16 Vs[2][128 * 64];
    __shared__ bf16 Ps[4][16 * 72];

    const int x = blockIdx.x;
    const int h = blockIdx.y, kvh = h >> 1;
    int a = (x & 1) ? (31 - (x >> 1)) : (x >> 1);
    const int qb = (h < 8) ? a : 31 - a;       // heavy/light pairing across CUs
    const int tid = threadIdx.x, w = tid >> 6, lane = tid & 63;
    const int l15 = lane & 15, quad = lane >> 4;
    const int qw0 = qb * 64 + w * 16;          // this wave's 16 q-rows

    bf16x8 qf[4];
    #pragma unroll
    for (int dk = 0; dk < 4; ++dk)
        qf[dk] = ld_frag(qkvb + (size_t)(qw0 + l15) * QKV_N +
                         h * HD + dk * 32 + quad * 8);

    f32x4 o[8];
    #pragma unroll
    for (int dt = 0; dt < 8; ++dt) o[dt] = f32x4{0.f, 0.f, 0.f, 0.f};
    float l_st = 0.f;                          // lane-partial sum of P

    // waves 0,1 stage K (64x128); waves 2,3 stage V^T (128x64)
    auto stage = [&](int t, int nb) {
        const int kt0 = t * 64;
        if (w < 2) {
            #pragma unroll
            for (int c = 0; c < 8; ++c) {
                int chunk = w * 8 + c;                 // 0..15
                int row = 4 * chunk + (lane >> 4);
                int ls = (lane & 15) ^ (row & 15);
                gload_lds16(qkvb + (size_t)(kt0 + row) * QKV_N + HID +
                            kvh * HD + ls * 8,
                            &Ks[nb][chunk * 512]);
            }
        } else {
            #pragma unroll
            for (int c = 0; c < 8; ++c) {
                int chunk = (w - 2) * 8 + c;           // 0..15
                int row = 8 * chunk + (lane >> 3);
                int ls = (lane & 7) ^ ((lane >> 3) & 7);
                gload_lds16(vT + (size_t)(kvh * HD + row) * S_LEN + kt0 + ls * 8,
                            &Vs[nb][chunk * 512]);
            }
        }
    };

    stage(0, 0);
    for (int t = 0; t <= qb; ++t) {
        const int pp = t & 1;
        const int kt0 = t * 64;
        __syncthreads();                  // drains stage(t)
        if (t < qb) stage(t + 1, pp ^ 1);

        // ---- S^T = K Q^T  (log2e pre-folded into q) ----
        f32x4 sc[4];
        #pragma unroll
        for (int mt = 0; mt < 4; ++mt) sc[mt] = f32x4{0.f, 0.f, 0.f, 0.f};
        __builtin_amdgcn_s_setprio(1);
        #pragma unroll
        for (int dk = 0; dk < 4; ++dk)
            #pragma unroll
            for (int mt = 0; mt < 4; ++mt) {
                bf16x8 kf = ld_frag(&Ks[pp][(mt * 16 + l15) * 128 +
                                            (((dk * 4 + quad) ^ l15) & 15) * 8]);
                sc[mt] = MFMA(kf, qf[dk], sc[mt]);
            }
        __builtin_amdgcn_s_setprio(0);

        // ---- causal mask (diagonal tile only: t == qb) ----
        if (kt0 + 63 > qw0) {
            #pragma unroll
            for (int mt = 0; mt < 4; ++mt)
                #pragma unroll
                for (int r = 0; r < 4; ++r) {
                    int kg = kt0 + mt * 16 + quad * 4 + r;
                    if (kg > qw0 + l15) sc[mt][r] = -1e30f;
                }
        }

        // ---- P = exp2(sc), lane-partial l, pack -> Ps ----
        #pragma unroll
        for (int mt = 0; mt < 4; ++mt) {
            union { uint2 u; bf16 hh[4]; } pk;
            #pragma unroll
            for (int r = 0; r < 4; ++r) {
                float p = exp2f(sc[mt][r]);
                pk.hh[r] = __float2bfloat16(p);
                l_st += p;
            }
            *(uint2*)&Ps[w][l15 * 72 + mt * 16 + quad * 4] = pk.u;
        }

        // ---- O^T += V^T P^T ----
        __builtin_amdgcn_s_setprio(1);
        #pragma unroll
        for (int kc = 0; kc < 2; ++kc) {
            bf16x8 pf = ld_frag(&Ps[w][l15 * 72 + kc * 32 + quad * 8]);
            #pragma unroll
            for (int dt = 0; dt < 8; ++dt) {
                bf16x8 vf = ld_frag(&Vs[pp][(dt * 16 + l15) * 64 +
                                            (((kc * 4 + quad) ^ (l15 & 7)) * 8)]);
                o[dt] = MFMA(vf, pf, o[dt]);
            }
        }
        __builtin_amdgcn_s_setprio(0);
    }

    // ---- epilogue: reduce l across quads once, divide, store ----
    l_st += __shfl_xor(l_st, 16, 64);
    l_st += __shfl_xor(l_st, 32, 64);
    float inv = 1.0f / l_st;
    int qg = qw0 + l15;
    #pragma unroll
    for (int dt = 0; dt < 8; ++dt) {
        union { uint2 u; bf16 hh[4]; } pk;
        #pragma unroll
        for (int r = 0; r < 4; ++r)
            pk.hh[r] = __float2bfloat16(o[dt][r] * inv);
        *(uint2*)&outb[(size_t)qg * HID + h * HD + dt * 16 + quad * 4] = pk.u;
    }
}

// ---------------------------------------------------------------------------
extern "C" void kernel_launch(void* const* d_in, const int* in_sizes, int n_in,
                              void* d_out, int out_size, void* d_ws, size_t ws_size,
                              hipStream_t stream) {
    const float* hidden = (const float*)d_in[0];
    const float* fcos   = (const float*)d_in[1];
    const float* fsin   = (const float*)d_in[2];
    // d_in[3] atten_mask: causal, applied analytically
    const float* Wq = (const float*)d_in[4];
    const float* Wk = (const float*)d_in[5];
    const float* Wv = (const float*)d_in[6];
    const float* Wo = (const float*)d_in[7];
    const float* qw = (const float*)d_in[8];
    const float* kw = (const float*)d_in[9];
    float* out = (float*)d_out;

    bf16* qkvb  = (bf16*)d_ws;                          // 2048 x 4096 (q|k normed)
    bf16* vT    = qkvb + (size_t)S_LEN * QKV_N;         // 1024 x 2048 (V^T)
    bf16* attnb = vT + (size_t)NKH * HD * S_LEN;        // 2048 x 2048
    bf16* wqkvb = attnb + (size_t)S_LEN * HID;          // 4096 x 2048
    bf16* hidb  = wqkvb + (size_t)QKV_N * HID;          // 2048 x 2048
    bf16* wob   = hidb + (size_t)S_LEN * HID;           // 2048 x 2048

    float* knew = out + (size_t)S_LEN * HID;
    float* vnew = knew + NKH * HD;

    // 0) all conversions in one launch (4M float4 units)
    cvt5<<<16384, 256, 0, stream>>>(
        hidden, Wq, Wk, Wv, Wo,
        hidb, wqkvb, wqkvb + (size_t)HID * HID,
        wqkvb + (size_t)(HID + NKH * HD) * HID, wob);

    // 1) QKV projection + fused RMSNorm/RoPE/QSCALE/V-transpose/knew/vnew
    //    128x128 tiles, BK=64, dbuf, quadrant waves -> 512 blocks
    gemm_qkv<<<dim3(QKV_N / 128, S_LEN / 128), 256, 0, stream>>>(
        hidb, wqkvb, qkvb, vT, fcos, fsin, qw, kw, knew, vnew);

    // 2) causal GQA flash attention (bf16 out), fixed-ref softmax, K-tile 64
    attn_mfma<<<dim3(32, NH), 256, 0, stream>>>(qkvb, vT, attnb);

    // 3) output projection (fp32 out), 128x128 tiles BK=64 dbuf -> 256 blocks
    gemm_n128<<<dim3(HID / 128, S_LEN / 128), 256, 0, stream>>>(
        attnb, wob, out, S_LEN, HID, HID);
}

// Round 3
// 237.950 us; speedup vs baseline: 1.0294x; 1.0294x over previous
//
#include <hip/hip_runtime.h>
#include <hip/hip_bf16.h>
#include <math.h>

#define S_LEN 2048
#define HID 2048
#define NH 16
#define NKH 8
#define HD 128
#define QKV_N 4096
#define SCALE 0.08838834764831845f
#define EPS 1e-6f
#define LOG2E 1.4426950408889634f
#define QSCALE (SCALE * LOG2E)     // fold log2(e) into q so p = exp2(score)

typedef __hip_bfloat16 bf16;
typedef unsigned int u32;
typedef __bf16 bf16x8 __attribute__((ext_vector_type(8)));
typedef float f32x4 __attribute__((ext_vector_type(4)));

#define MFMA(a, b, c) __builtin_amdgcn_mfma_f32_16x16x32_bf16(a, b, c, 0, 0, 0)

static __device__ __forceinline__ bf16x8 ld_frag(const bf16* p) {
    return __builtin_bit_cast(bf16x8, *(const uint4*)p);
}

// async global->LDS, 16 B per lane. LDS dest = wave-uniform base + lane*16.
static __device__ __forceinline__ void gload_lds16(const void* g, void* l) {
    __builtin_amdgcn_global_load_lds(
        (const __attribute__((address_space(1))) u32*)g,
        (__attribute__((address_space(3))) u32*)l, 16, 0, 0);
}

// ---------------------------------------------------------------------------
// merged fp32 -> bf16: hidden | Wq | Wk | Wv | Wo in one launch.
// float4-unit thresholds: 1M | 2M | 2.5M | 3M | 4M. grid = 16384 x 256.
// ---------------------------------------------------------------------------
__global__ __launch_bounds__(256) void cvt5(
    const float* __restrict__ s0, const float* __restrict__ s1,
    const float* __restrict__ s2, const float* __restrict__ s3,
    const float* __restrict__ s4,
    bf16* __restrict__ d0, bf16* __restrict__ d1, bf16* __restrict__ d2,
    bf16* __restrict__ d3, bf16* __restrict__ d4)
{
    int i = blockIdx.x * 256 + threadIdx.x;
    const float* s; bf16* d; int off;
    if (i < (1 << 20))                   { s = s0; d = d0; off = 0; }
    else if (i < (2 << 20))              { s = s1; d = d1; off = 1 << 20; }
    else if (i < (2 << 20) + (1 << 19))  { s = s2; d = d2; off = 2 << 20; }
    else if (i < (3 << 20))              { s = s3; d = d3; off = (2 << 20) + (1 << 19); }
    else                                 { s = s4; d = d4; off = 3 << 20; }
    int j = i - off;
    float4 v = ((const float4*)s)[j];
    bf16* p = d + 4 * (size_t)j;
    p[0] = __float2bfloat16(v.x);
    p[1] = __float2bfloat16(v.y);
    p[2] = __float2bfloat16(v.z);
    p[3] = __float2bfloat16(v.w);
}

// ---------------------------------------------------------------------------
// QKV GEMM + fused epilogue (proven R0 structure, unchanged).
// 128x128 tiles, BK=64, DOUBLE-BUFFERED global_load_lds staging
// (1 barrier/iter, 2 blocks/CU -> cross-block overlap covers barrier drain).
// Wave = 64x64 quadrant as 4x4 MFMA grid -> 8 LDS reads per 16 MFMA.
//   q heads: RMSNorm(qw)+RoPE, * SCALE*LOG2E -> qkvb
//   k heads: RMSNorm(kw)+RoPE -> qkvb; row 2047 -> knew (fp32)
//   v heads: raw -> vT transposed (packed uint2); row 2047 -> vnew
// ---------------------------------------------------------------------------
__global__ __launch_bounds__(256, 2) void gemm_qkv(
    const bf16* __restrict__ A, const bf16* __restrict__ B,
    bf16* __restrict__ qkvb, bf16* __restrict__ vT,
    const float* __restrict__ fcos, const float* __restrict__ fsin,
    const float* __restrict__ qw, const float* __restrict__ kw,
    float* __restrict__ knew, float* __restrict__ vnew)
{
    __shared__ bf16 As[2][128 * 64];
    __shared__ bf16 Bs[2][128 * 64];
    __shared__ float red[2][2][64];    // [row-half][col-wave][row]
    const int tid = threadIdx.x;
    const int n0 = blockIdx.x * 128, m0 = blockIdx.y * 128;
    const int w = tid >> 6, lane = tid & 63;
    const int l15 = lane & 15, quad = lane >> 4;
    const int wr = (w >> 1) * 64;      // wave row base
    const int wcg = (w & 1) * 32;      // wave column group base

    f32x4 acc[4][4];
    #pragma unroll
    for (int i = 0; i < 4; ++i)
        #pragma unroll
        for (int j = 0; j < 4; ++j)
            acc[i][j] = f32x4{0.f, 0.f, 0.f, 0.f};

    // staging: chunk = 8 rows x 64 k; lane -> row (lane>>3), phys slot lane&7
    const int srow8 = lane >> 3;
    const int sls = ((lane & 7) ^ srow8) * 8;   // logical k-slot fetched

    auto stage = [&](int k0, int nb) {
        #pragma unroll
        for (int j = 0; j < 8; ++j) {
            int c = 8 * w + j;                 // 0..31: 16 A-chunks, 16 B-chunks
            if (c < 16) {
                int row = c * 8 + srow8;
                gload_lds16(A + (size_t)(m0 + row) * HID + k0 + sls, &As[nb][c * 512]);
            } else {
                int row = (c - 16) * 8 + srow8;
                gload_lds16(B + (size_t)(n0 + row) * HID + k0 + sls, &Bs[nb][(c - 16) * 512]);
            }
        }
    };

    stage(0, 0);
    for (int kt = 0; kt < HID / 64; ++kt) {
        const int pp = kt & 1;
        __syncthreads();                       // drains stage(kt) -> buf pp ready
        if (kt + 1 < HID / 64) stage((kt + 1) * 64, pp ^ 1);

        #pragma unroll
        for (int kc = 0; kc < 2; ++kc) {
            const int ph = ((kc * 4 + quad) ^ (l15 & 7)) * 8;
            bf16x8 av[4], bv[4];
            #pragma unroll
            for (int i = 0; i < 4; ++i)
                av[i] = ld_frag(&As[pp][(wr + i * 16 + l15) * 64 + ph]);
            #pragma unroll
            for (int j = 0; j < 4; ++j)
                bv[j] = ld_frag(&Bs[pp][(wcg + (j & 1) * 16 + (j >> 1) * 64 + l15) * 64 + ph]);
            #pragma unroll
            for (int i = 0; i < 4; ++i)
                #pragma unroll
                for (int j = 0; j < 4; ++j)
                    acc[i][j] = MFMA(av[i], bv[j], acc[i][j]);
        }
    }

    const int hblk = n0 >> 7;          // 0..15 q | 16..23 k | 24..31 v
    if (hblk < 24) {
        // ---- cross-wave sumsq exchange ----
        float ssq[4][4];
        #pragma unroll
        for (int i = 0; i < 4; ++i)
            #pragma unroll
            for (int rr = 0; rr < 4; ++rr) {
                float ss = 0.f;
                #pragma unroll
                for (int j = 0; j < 4; ++j) ss += acc[i][j][rr] * acc[i][j][rr];
                ss += __shfl_xor(ss, 1);
                ss += __shfl_xor(ss, 2);
                ss += __shfl_xor(ss, 4);
                ss += __shfl_xor(ss, 8);
                ssq[i][rr] = ss;
                if (l15 == 0)
                    red[w >> 1][w & 1][i * 16 + quad * 4 + rr] = ss;
            }
        __syncthreads();

        const float* wgt = (hblk < 16) ? qw : kw;
        float wv[4];
        #pragma unroll
        for (int j = 0; j < 4; ++j)
            wv[j] = wgt[wcg + (j & 1) * 16 + (j >> 1) * 64 + l15];
        const size_t cb = (hblk < 16) ? (size_t)hblk * HD
                                      : (size_t)HID + (size_t)(hblk - 16) * HD;

        #pragma unroll
        for (int i = 0; i < 4; ++i)
            #pragma unroll
            for (int rr = 0; rr < 4; ++rr) {
                int rloc = i * 16 + quad * 4 + rr;
                int srow = m0 + wr + rloc;
                float tot = ssq[i][rr] + red[w >> 1][(w & 1) ^ 1][rloc];
                float rrn = rsqrtf(tot * (1.0f / 128.0f) + EPS);
                float x[4], res[4];
                #pragma unroll
                for (int j = 0; j < 4; ++j) x[j] = acc[i][j][rr] * rrn * wv[j];
                #pragma unroll
                for (int j2 = 0; j2 < 2; ++j2) {
                    float c = fcos[srow * 64 + wcg + j2 * 16 + l15];
                    float s = fsin[srow * 64 + wcg + j2 * 16 + l15];
                    res[j2]     = x[j2] * c - x[j2 + 2] * s;
                    res[j2 + 2] = x[j2] * s + x[j2 + 2] * c;
                }
                if (hblk < 16) {
                    #pragma unroll
                    for (int j = 0; j < 4; ++j)
                        qkvb[(size_t)srow * QKV_N + cb + wcg + (j & 1) * 16 +
                             (j >> 1) * 64 + l15] = __float2bfloat16(res[j] * QSCALE);
                } else {
                    #pragma unroll
                    for (int j = 0; j < 4; ++j)
                        qkvb[(size_t)srow * QKV_N + cb + wcg + (j & 1) * 16 +
                             (j >> 1) * 64 + l15] = __float2bfloat16(res[j]);
                    if (srow == S_LEN - 1) {
                        #pragma unroll
                        for (int j = 0; j < 4; ++j)
                            knew[(hblk - 16) * HD + wcg + (j & 1) * 16 +
                                 (j >> 1) * 64 + l15] = res[j];
                    }
                }
            }
    } else {
        const int kh = hblk - 24;
        #pragma unroll
        for (int i = 0; i < 4; ++i) {
            int rowbase = m0 + wr + i * 16 + quad * 4;
            #pragma unroll
            for (int j = 0; j < 4; ++j) {
                int d = wcg + (j & 1) * 16 + (j >> 1) * 64 + l15;
                union { uint2 u; bf16 hh[4]; } pk;
                #pragma unroll
                for (int r = 0; r < 4; ++r)
                    pk.hh[r] = __float2bfloat16(acc[i][j][r]);
                *(uint2*)&vT[(size_t)(kh * HD + d) * S_LEN + rowbase] = pk.u;
                if (rowbase == S_LEN - 4)
                    vnew[kh * HD + d] = acc[i][j][3];
            }
        }
    }
}

// ---------------------------------------------------------------------------
// 128(M)x64(N)-tile GEMM, BK=64, double-buffered, fp32 out — out-projection.
// REVERTED to R0: 512 blocks = 2/CU gives cross-block overlap that the
// 128x128 (256 blocks = 1/CU) variant lost. LDS 48 KB.
// ---------------------------------------------------------------------------
__global__ __launch_bounds__(256, 2) void gemm_n64(
    const bf16* __restrict__ A, const bf16* __restrict__ B,
    float* __restrict__ C, int M, int N, int K)
{
    __shared__ bf16 As[2][128 * 64];
    __shared__ bf16 Bs[2][64 * 64];
    const int tid = threadIdx.x;
    const int n0 = blockIdx.x * 64, m0 = blockIdx.y * 128;
    const int w = tid >> 6, lane = tid & 63;
    const int l15 = lane & 15, quad = lane >> 4;

    f32x4 acc[2][4];
    #pragma unroll
    for (int i = 0; i < 2; ++i)
        #pragma unroll
        for (int j = 0; j < 4; ++j)
            acc[i][j] = f32x4{0.f, 0.f, 0.f, 0.f};

    const int srow8 = lane >> 3;
    const int sls = ((lane & 7) ^ srow8) * 8;

    auto stage = [&](int k0, int nb) {
        #pragma unroll
        for (int j = 0; j < 6; ++j) {
            int c = 6 * w + j;                 // 0..23: 16 A-chunks, 8 B-chunks
            if (c < 16) {
                int row = c * 8 + srow8;
                gload_lds16(A + (size_t)(m0 + row) * K + k0 + sls, &As[nb][c * 512]);
            } else {
                int row = (c - 16) * 8 + srow8;
                gload_lds16(B + (size_t)(n0 + row) * K + k0 + sls, &Bs[nb][(c - 16) * 512]);
            }
        }
    };

    stage(0, 0);
    for (int kt = 0; kt < K / 64; ++kt) {
        const int pp = kt & 1;
        __syncthreads();
        if (kt + 1 < K / 64) stage((kt + 1) * 64, pp ^ 1);

        #pragma unroll
        for (int kc = 0; kc < 2; ++kc) {
            const int ph = ((kc * 4 + quad) ^ (l15 & 7)) * 8;
            bf16x8 av[2], bv[4];
            av[0] = ld_frag(&As[pp][(w * 32 + l15) * 64 + ph]);
            av[1] = ld_frag(&As[pp][(w * 32 + 16 + l15) * 64 + ph]);
            #pragma unroll
            for (int j = 0; j < 4; ++j)
                bv[j] = ld_frag(&Bs[pp][(j * 16 + l15) * 64 + ph]);
            #pragma unroll
            for (int i = 0; i < 2; ++i)
                #pragma unroll
                for (int j = 0; j < 4; ++j)
                    acc[i][j] = MFMA(av[i], bv[j], acc[i][j]);
        }
    }

    #pragma unroll
    for (int i = 0; i < 2; ++i)
        #pragma unroll
        for (int j = 0; j < 4; ++j)
            #pragma unroll
            for (int r = 0; r < 4; ++r)
                C[(size_t)(m0 + w * 32 + i * 16 + quad * 4 + r) * N +
                  n0 + j * 16 + l15] = acc[i][j][r];
}

// ---------------------------------------------------------------------------
// Flash attention — R3: PV ownership transposed to cut LDS-read duplication.
// QK^T unchanged (wave owns q=16, Q in regs: 16 reads / 16 MFMA, optimal).
// PV: wave now owns d-slice 32 x all 64 q (was q=16 x d=128): vf 4 reads
// (own d-slice only — V tile no longer read 4x across waves) + pf 8 reads
// (all waves' Ps) = 12 reads / 16 MFMA (was 18). Needs one extra barrier per
// iter for cross-wave Ps visibility — issued as raw s_barrier + lgkmcnt(0)
// ONLY, so the in-flight K/V prefetch (vmcnt) is NOT drained mid-iteration.
// Epilogue: softmax denominators exchanged via lred[4][16]; store covers
// d in [w*32, w*32+32) x q in [0,64).
// ---------------------------------------------------------------------------
__global__ __launch_bounds__(256, 2) void attn_mfma(
    const bf16* __restrict__ qkvb, const bf16* __restrict__ vT,
    bf16* __restrict__ outb)
{
    __shared__ bf16 Ks[2][64 * 128];
    __shared__ bf16 Vs[2][128 * 64];
    __shared__ bf16 Ps[4][16 * 72];
    __shared__ float lred[4][16];

    const int x = blockIdx.x;
    const int h = blockIdx.y, kvh = h >> 1;
    int a = (x & 1) ? (31 - (x >> 1)) : (x >> 1);
    const int qb = (h < 8) ? a : 31 - a;       // heavy/light pairing across CUs
    const int tid = threadIdx.x, w = tid >> 6, lane = tid & 63;
    const int l15 = lane & 15, quad = lane >> 4;
    const int qw0 = qb * 64 + w * 16;          // this wave's 16 q-rows (QK^T)

    bf16x8 qf[4];
    #pragma unroll
    for (int dk = 0; dk < 4; ++dk)
        qf[dk] = ld_frag(qkvb + (size_t)(qw0 + l15) * QKV_N +
                         h * HD + dk * 32 + quad * 8);

    // o[dt*4 + j]: rows d = w*32 + dt*16 + quad*4 + r, cols q = j*16 + l15
    f32x4 o[8];
    #pragma unroll
    for (int dt = 0; dt < 8; ++dt) o[dt] = f32x4{0.f, 0.f, 0.f, 0.f};
    float l_st = 0.f;                          // lane-partial sum of P

    // waves 0,1 stage K (64x128); waves 2,3 stage V^T (128x64)
    auto stage = [&](int t, int nb) {
        const int kt0 = t * 64;
        if (w < 2) {
            #pragma unroll
            for (int c = 0; c < 8; ++c) {
                int chunk = w * 8 + c;                 // 0..15
                int row = 4 * chunk + (lane >> 4);
                int ls = (lane & 15) ^ (row & 15);
                gload_lds16(qkvb + (size_t)(kt0 + row) * QKV_N + HID +
                            kvh * HD + ls * 8,
                            &Ks[nb][chunk * 512]);
            }
        } else {
            #pragma unroll
            for (int c = 0; c < 8; ++c) {
                int chunk = (w - 2) * 8 + c;           // 0..15
                int row = 8 * chunk + (lane >> 3);
                int ls = (lane & 7) ^ ((lane >> 3) & 7);
                gload_lds16(vT + (size_t)(kvh * HD + row) * S_LEN + kt0 + ls * 8,
                            &Vs[nb][chunk * 512]);
            }
        }
    };

    stage(0, 0);
    for (int t = 0; t <= qb; ++t) {
        const int pp = t & 1;
        const int kt0 = t * 64;
        __syncthreads();                  // drains stage(t)
        if (t < qb) stage(t + 1, pp ^ 1);

        // ---- S^T = K Q^T  (log2e pre-folded into q) ----
        f32x4 sc[4];
        #pragma unroll
        for (int mt = 0; mt < 4; ++mt) sc[mt] = f32x4{0.f, 0.f, 0.f, 0.f};
        #pragma unroll
        for (int dk = 0; dk < 4; ++dk)
            #pragma unroll
            for (int mt = 0; mt < 4; ++mt) {
                bf16x8 kf = ld_frag(&Ks[pp][(mt * 16 + l15) * 128 +
                                            (((dk * 4 + quad) ^ l15) & 15) * 8]);
                sc[mt] = MFMA(kf, qf[dk], sc[mt]);
            }

        // ---- causal mask (diagonal tile only: t == qb) ----
        if (kt0 + 63 > qw0) {
            #pragma unroll
            for (int mt = 0; mt < 4; ++mt)
                #pragma unroll
                for (int r = 0; r < 4; ++r) {
                    int kg = kt0 + mt * 16 + quad * 4 + r;
                    if (kg > qw0 + l15) sc[mt][r] = -1e30f;
                }
        }

        // ---- P = exp2(sc), lane-partial l, pack -> Ps ----
        #pragma unroll
        for (int mt = 0; mt < 4; ++mt) {
            union { uint2 u; bf16 hh[4]; } pk;
            #pragma unroll
            for (int r = 0; r < 4; ++r) {
                float p = exp2f(sc[mt][r]);
                pk.hh[r] = __float2bfloat16(p);
                l_st += p;
            }
            *(uint2*)&Ps[w][l15 * 72 + mt * 16 + quad * 4] = pk.u;
        }

        // cross-wave Ps visibility: own ds_writes drained, then raw barrier
        // (NO vmcnt drain — stage(t+1) stays in flight).
        asm volatile("s_waitcnt lgkmcnt(0)" ::: "memory");
        __builtin_amdgcn_s_barrier();

        // ---- O^T += V^T P^T, wave owns d-slice [w*32, w*32+32) x q 64 ----
        #pragma unroll
        for (int kc = 0; kc < 2; ++kc) {
            bf16x8 pf[4];
            #pragma unroll
            for (int j = 0; j < 4; ++j)
                pf[j] = ld_frag(&Ps[j][l15 * 72 + kc * 32 + quad * 8]);
            #pragma unroll
            for (int dt = 0; dt < 2; ++dt) {
                bf16x8 vf = ld_frag(&Vs[pp][((w * 2 + dt) * 16 + l15) * 64 +
                                            (((kc * 4 + quad) ^ (l15 & 7)) * 8)]);
                #pragma unroll
                for (int j = 0; j < 4; ++j)
                    o[dt * 4 + j] = MFMA(vf, pf[j], o[dt * 4 + j]);
            }
        }
        // next iter's loop-top __syncthreads orders PV reads vs Ps rewrite
    }

    // ---- epilogue: exchange per-q-row denominators, divide, store ----
    l_st += __shfl_xor(l_st, 16, 64);
    l_st += __shfl_xor(l_st, 32, 64);
    if (lane < 16) lred[w][lane] = l_st;
    __syncthreads();
    #pragma unroll
    for (int j = 0; j < 4; ++j) {
        float inv = 1.0f / lred[j][l15];
        int qg = qb * 64 + j * 16 + l15;
        #pragma unroll
        for (int dt = 0; dt < 2; ++dt) {
            union { uint2 u; bf16 hh[4]; } pk;
            #pragma unroll
            for (int r = 0; r < 4; ++r)
                pk.hh[r] = __float2bfloat16(o[dt * 4 + j][r] * inv);
            *(uint2*)&outb[(size_t)qg * HID + h * HD + w * 32 + dt * 16 + quad * 4] = pk.u;
        }
    }
}

// ---------------------------------------------------------------------------
extern "C" void kernel_launch(void* const* d_in, const int* in_sizes, int n_in,
                              void* d_out, int out_size, void* d_ws, size_t ws_size,
                              hipStream_t stream) {
    const float* hidden = (const float*)d_in[0];
    const float* fcos   = (const float*)d_in[1];
    const float* fsin   = (const float*)d_in[2];
    // d_in[3] atten_mask: causal, applied analytically
    const float* Wq = (const float*)d_in[4];
    const float* Wk = (const float*)d_in[5];
    const float* Wv = (const float*)d_in[6];
    const float* Wo = (const float*)d_in[7];
    const float* qw = (const float*)d_in[8];
    const float* kw = (const float*)d_in[9];
    float* out = (float*)d_out;

    bf16* qkvb  = (bf16*)d_ws;                          // 2048 x 4096 (q|k normed)
    bf16* vT    = qkvb + (size_t)S_LEN * QKV_N;         // 1024 x 2048 (V^T)
    bf16* attnb = vT + (size_t)NKH * HD * S_LEN;        // 2048 x 2048
    bf16* wqkvb = attnb + (size_t)S_LEN * HID;          // 4096 x 2048
    bf16* hidb  = wqkvb + (size_t)QKV_N * HID;          // 2048 x 2048
    bf16* wob   = hidb + (size_t)S_LEN * HID;           // 2048 x 2048

    float* knew = out + (size_t)S_LEN * HID;
    float* vnew = knew + NKH * HD;

    // 0) all conversions in one launch (4M float4 units)
    cvt5<<<16384, 256, 0, stream>>>(
        hidden, Wq, Wk, Wv, Wo,
        hidb, wqkvb, wqkvb + (size_t)HID * HID,
        wqkvb + (size_t)(HID + NKH * HD) * HID, wob);

    // 1) QKV projection + fused RMSNorm/RoPE/QSCALE/V-transpose/knew/vnew
    //    128x128 tiles, BK=64, dbuf, quadrant waves -> 512 blocks
    gemm_qkv<<<dim3(QKV_N / 128, S_LEN / 128), 256, 0, stream>>>(
        hidb, wqkvb, qkvb, vT, fcos, fsin, qw, kw, knew, vnew);

    // 2) causal GQA flash attention (bf16 out), fixed-ref softmax, K-tile 64
    attn_mfma<<<dim3(32, NH), 256, 0, stream>>>(qkvb, vT, attnb);

    // 3) output projection (fp32 out), 128x64 tiles BK=64 dbuf -> 512 blocks
    gemm_n64<<<dim3(HID / 64, S_LEN / 128), 256, 0, stream>>>(
        attnb, wob, out, S_LEN, HID, HID);
}